// Round 2
// baseline (569.164 us; speedup 1.0000x reference)
//
#include <hip/hip_runtime.h>
#include <hip/hip_bf16.h>

// BaseQVLayer: xp = x@Wx+bx; yp = y@Wy+by; At[j,i] = 2*(yp_j . xp_i)/(||xp_i||^2+||yp_j||^2);
// gwf = At@xp; out = relu(gwf@Wg+bg).  bf16 MFMA 16x16x32, fp32 accum.
//
// R2: global_load_lds(16B) staging (m97 pattern, unpadded LDS stride 32),
//     split-K G4 (4 chunks, gridDim.z) + f32 atomicAdd epilogue into gwf_f32.
//
// Workspace (162.6 MB, <= proven 163.1):
//   At   [8192*8192] bf16 (128 MB)
//   xpb  [8192*512] bf16 \ gwf_f32 [8192*512] f32 (16 MB) aliases xpb+ypb
//   ypb  [8192*512] bf16 /  (both dead after G3)
//   xpT  [512*8192] bf16
//   WxT/WyT/WgT bf16, Dx/Dy f32

typedef __attribute__((ext_vector_type(8))) short bf16x8;
typedef __attribute__((ext_vector_type(4))) short bf16x4;
typedef __attribute__((ext_vector_type(4))) float f32x4;

__device__ __forceinline__ short f2b(float f) {
    unsigned int u = __builtin_bit_cast(unsigned int, f);
    unsigned int r = (u + 0x7fffu + ((u >> 16) & 1u)) >> 16;
    return (short)r;
}

// async global->LDS, 16 bytes/lane. LDS dest must be wave-uniform base + lane*16.
__device__ __forceinline__ void cp16(const void* g, void* l) {
    __builtin_amdgcn_global_load_lds(
        (const __attribute__((address_space(1))) void*)g,
        (__attribute__((address_space(3))) void*)l, 16, 0, 0);
}

constexpr int EPI_XP   = 0;  // +bias, store bf16, atomic row-norm accumulate
constexpr int EPI_AT   = 1;  // 2/(Dcol[n]+Drow[m]) scale, store bf16
constexpr int EPI_PART = 2;  // f32 atomicAdd into outf (split-K partial)
constexpr int EPI_OUT  = 3;  // +bias, relu, store f32

// C = A @ Bt^T. 128x128 tile, 256 thr, 4 waves x (64x64 via 4x4 MFMA 16x16x32).
// LDS tiles 128x32 UNPADDED (stride 32 elems) so global_load_lds lane mapping
// (offset = seg*16B, seg wave-contiguous) lands correctly [m104/m108 caveat].
// K param = per-chunk K; blockIdx.z selects chunk (kbase = z*K).
template<int EPI, bool AF32>
__global__ __launch_bounds__(256)
void gemm_bt(const void* __restrict__ Aptr, int lda,
             const short* __restrict__ Bt, int ldb,
             int M, int N, int K,
             const float* __restrict__ bias,
             short* __restrict__ outb,
             float* __restrict__ outf,
             float* __restrict__ Dacc,
             const float* __restrict__ Drow,
             const float* __restrict__ Dcol)
{
    __shared__ __align__(16) short As[128 * 32];
    __shared__ __align__(16) short Bs[128 * 32];

    const int tid  = threadIdx.x;
    const int wave = tid >> 6;
    const int lane = tid & 63;
    const int quad = lane >> 4;
    const int l15  = lane & 15;
    const int wm   = (wave >> 1) * 64;
    const int wn   = (wave & 1) * 64;
    const int bm   = blockIdx.y * 128;
    const int bn   = blockIdx.x * 128;
    const int kbase = blockIdx.z * K;

    f32x4 acc[4][4];
#pragma unroll
    for (int i = 0; i < 4; i++)
#pragma unroll
        for (int j = 0; j < 4; j++)
            acc[i][j] = f32x4{0.f, 0.f, 0.f, 0.f};

    for (int k0 = 0; k0 < K; k0 += 32) {
        const int kk = kbase + k0;
        if (AF32) {
            const float* Af = (const float*)Aptr;
#pragma unroll
            for (int s = 0; s < 4; s++) {
                int seg = tid + 256 * s;          // 1024 segs: 128 rows x 8 float4
                int row = seg >> 3, c4 = seg & 7;
                const float4 v = *(const float4*)&Af[(size_t)(bm + row) * lda + kk + c4 * 4];
                bf16x4 b;
                b[0] = f2b(v.x); b[1] = f2b(v.y); b[2] = f2b(v.z); b[3] = f2b(v.w);
                *(bf16x4*)&As[row * 32 + c4 * 4] = b;
            }
        } else {
            const short* Ab = (const short*)Aptr;
#pragma unroll
            for (int s = 0; s < 2; s++) {
                int seg = tid + 256 * s;          // 512 segs: 128 rows x 4 x 8 bf16
                int row = seg >> 2, c8 = seg & 3;
                cp16(&Ab[(size_t)(bm + row) * lda + kk + c8 * 8], &As[seg * 8]);
            }
        }
#pragma unroll
        for (int s = 0; s < 2; s++) {
            int seg = tid + 256 * s;
            int row = seg >> 2, c8 = seg & 3;
            cp16(&Bt[(size_t)(bn + row) * ldb + kk + c8 * 8], &Bs[seg * 8]);
        }
        __syncthreads();   // drains vmcnt (global_load_lds) + lgkmcnt

        bf16x8 af[4], bfr[4];
#pragma unroll
        for (int i = 0; i < 4; i++)
            af[i] = *(const bf16x8*)&As[(wm + i * 16 + l15) * 32 + quad * 8];
#pragma unroll
        for (int j = 0; j < 4; j++)
            bfr[j] = *(const bf16x8*)&Bs[(wn + j * 16 + l15) * 32 + quad * 8];
#pragma unroll
        for (int i = 0; i < 4; i++)
#pragma unroll
            for (int j = 0; j < 4; j++)
                acc[i][j] = __builtin_amdgcn_mfma_f32_16x16x32_bf16(af[i], bfr[j], acc[i][j], 0, 0, 0);
        __syncthreads();
    }

    // C/D layout: col = lane&15, row = quad*4 + r  [m89/m91]
#pragma unroll
    for (int im = 0; im < 4; im++) {
#pragma unroll
        for (int r = 0; r < 4; r++) {
            const int gm = bm + wm + im * 16 + quad * 4 + r;
            if (EPI == EPI_XP) {
                float s = 0.f;
#pragma unroll
                for (int jn = 0; jn < 4; jn++) {
                    const int gn = bn + wn + jn * 16 + l15;
                    float v = acc[im][jn][r] + bias[gn];
                    outb[(size_t)gm * N + gn] = f2b(v);
                    s += v * v;
                }
#pragma unroll
                for (int m = 1; m < 16; m <<= 1) s += __shfl_xor(s, m, 64);
                if (l15 == 0) atomicAdd(&Dacc[gm], s);
            } else if (EPI == EPI_AT) {
                const float dy = Drow[gm];
#pragma unroll
                for (int jn = 0; jn < 4; jn++) {
                    const int gn = bn + wn + jn * 16 + l15;
                    float v = 2.f * acc[im][jn][r] / (Dcol[gn] + dy);
                    outb[(size_t)gm * N + gn] = f2b(v);
                }
            } else if (EPI == EPI_PART) {
#pragma unroll
                for (int jn = 0; jn < 4; jn++) {
                    const int gn = bn + wn + jn * 16 + l15;
                    atomicAdd(&outf[(size_t)gm * N + gn], acc[im][jn][r]);
                }
            } else {
#pragma unroll
                for (int jn = 0; jn < 4; jn++) {
                    const int gn = bn + wn + jn * 16 + l15;
                    float v = acc[im][jn][r] + bias[gn];
                    outf[(size_t)gm * N + gn] = fmaxf(v, 0.f);
                }
            }
        }
    }
}

__global__ __launch_bounds__(256)
void transpose_f32_bf16(const float* __restrict__ in, short* __restrict__ out, int R, int C)
{
    __shared__ short t[32][33];
    const int tx = threadIdx.x, ty = threadIdx.y;
    const int bx = blockIdx.x * 32, by = blockIdx.y * 32;
#pragma unroll
    for (int i = 0; i < 32; i += 8)
        t[ty + i][tx] = f2b(in[(size_t)(by + ty + i) * C + bx + tx]);
    __syncthreads();
#pragma unroll
    for (int i = 0; i < 32; i += 8)
        out[(size_t)(bx + ty + i) * R + by + tx] = t[tx][ty + i];
}

__global__ __launch_bounds__(256)
void transpose_bf16(const short* __restrict__ in, short* __restrict__ out, int R, int C)
{
    __shared__ short t[32][33];
    const int tx = threadIdx.x, ty = threadIdx.y;
    const int bx = blockIdx.x * 32, by = blockIdx.y * 32;
#pragma unroll
    for (int i = 0; i < 32; i += 8)
        t[ty + i][tx] = in[(size_t)(by + ty + i) * C + bx + tx];
    __syncthreads();
#pragma unroll
    for (int i = 0; i < 32; i += 8)
        out[(size_t)(bx + ty + i) * R + by + tx] = t[tx][ty + i];
}

extern "C" void kernel_launch(void* const* d_in, const int* in_sizes, int n_in,
                              void* d_out, int out_size, void* d_ws, size_t ws_size,
                              hipStream_t stream)
{
    const float* x  = (const float*)d_in[0];   // [8192,1024]
    const float* y  = (const float*)d_in[1];   // [8192,1024]
    const float* Wx = (const float*)d_in[2];   // [1024, 512]
    const float* bx = (const float*)d_in[3];   // [512]
    const float* Wy = (const float*)d_in[4];   // [1024, 512]
    const float* by = (const float*)d_in[5];   // [512]
    const float* Wg = (const float*)d_in[6];   // [512, 512]
    const float* bg = (const float*)d_in[7];   // [512]
    float* out = (float*)d_out;                // [8192, 512] f32

    char* p = (char*)d_ws;
    short* At   = (short*)p; p += (size_t)8192 * 8192 * 2;
    short* xpb  = (short*)p; p += (size_t)8192 * 512 * 2;
    short* ypb  = (short*)p; p += (size_t)8192 * 512 * 2;
    float* gwf  = (float*)xpb;                 // 16 MB, aliases xpb+ypb (dead after G3)
    short* xpT  = (short*)p; p += (size_t)512 * 8192 * 2;
    short* WxT  = (short*)p; p += (size_t)512 * 1024 * 2;
    short* WyT  = (short*)p; p += (size_t)512 * 1024 * 2;
    short* WgT  = (short*)p; p += (size_t)512 * 512 * 2;
    float* Dx   = (float*)p; p += (size_t)8192 * 4;
    float* Dy   = (float*)p; p += (size_t)8192 * 4;

    hipMemsetAsync(Dx, 0, 2 * 8192 * sizeof(float), stream);  // Dx,Dy contiguous

    dim3 tb(32, 8);
    transpose_f32_bf16<<<dim3(512 / 32, 1024 / 32), tb, 0, stream>>>(Wx, WxT, 1024, 512);
    transpose_f32_bf16<<<dim3(512 / 32, 1024 / 32), tb, 0, stream>>>(Wy, WyT, 1024, 512);
    transpose_f32_bf16<<<dim3(512 / 32, 512 / 32),  tb, 0, stream>>>(Wg, WgT, 512, 512);

    // G1/G2: projections + row norms
    gemm_bt<EPI_XP, true><<<dim3(4, 64, 1), 256, 0, stream>>>(
        x, 1024, WxT, 1024, 8192, 512, 1024, bx, xpb, nullptr, Dx, nullptr, nullptr);
    gemm_bt<EPI_XP, true><<<dim3(4, 64, 1), 256, 0, stream>>>(
        y, 1024, WyT, 1024, 8192, 512, 1024, by, ypb, nullptr, Dy, nullptr, nullptr);

    transpose_bf16<<<dim3(512 / 32, 8192 / 32), tb, 0, stream>>>(xpb, xpT, 8192, 512);

    // G3: At[j,i] = 2*(yp_j . xp_i)/(Dx[i]+Dy[j])
    gemm_bt<EPI_AT, false><<<dim3(64, 64, 1), 256, 0, stream>>>(
        ypb, 512, xpb, 512, 8192, 8192, 512, nullptr, At, nullptr, nullptr, Dy, Dx);

    // gwf_f32 aliases xpb/ypb (dead now); zero, then split-K G4 accumulates into it
    hipMemsetAsync(gwf, 0, (size_t)8192 * 512 * sizeof(float), stream);

    // G4: gwf = At @ xp, split-K 4 x 2048, f32 atomic accumulate
    gemm_bt<EPI_PART, false><<<dim3(4, 64, 4), 256, 0, stream>>>(
        At, 8192, xpT, 8192, 8192, 512, 2048, nullptr, nullptr, gwf, nullptr, nullptr, nullptr);

    // G5: out = relu(gwf @ Wg + bg)   (A is f32 gwf -> staged/converted in-kernel)
    gemm_bt<EPI_OUT, true><<<dim3(4, 64, 1), 256, 0, stream>>>(
        gwf, 512, WgT, 512, 8192, 512, 512, bg, nullptr, out, nullptr, nullptr, nullptr);
}

// Round 3
// 391.740 us; speedup vs baseline: 1.4529x; 1.4529x over previous
//
#include <hip/hip_runtime.h>
#include <hip/hip_bf16.h>

// BaseQVLayer: xp = x@Wx+bx; yp = y@Wy+by; At[j,i] = 2*(yp_j . xp_i)/(||xp_i||^2+||yp_j||^2);
// gwf = At@xp; out = relu(gwf@Wg+bg).  bf16 MFMA 16x16x32, fp32 accum.
//
// R3: distinct kernel names per stage; XCD-aware swizzles (agg: 4 bn-blocks
// sharing an At slice -> same XCD; aff: 8x8 block supertile per XCD so the
// 2 MB xp/yp working set fits L2); G4 split-K z=2 -> bf16 partials (no atomics,
// no memset), summed in G5's A-staging; G1/G2/G5 use M-tile 64 (512 blocks).
//
// Workspace: At[8192*8192]bf16(128MB) | xpb | ypb | xpT | WxT | WyT | WgT | Dx,Dy
// p0/p1 (G4 partials, 8192*512 bf16 each) alias xpb/ypb (dead after G3).

typedef __attribute__((ext_vector_type(8))) short bf16x8;
typedef __attribute__((ext_vector_type(4))) short bf16x4;
typedef __attribute__((ext_vector_type(4))) float f32x4;

__device__ __forceinline__ short f2b(float f) {
    unsigned int u = __builtin_bit_cast(unsigned int, f);
    unsigned int r = (u + 0x7fffu + ((u >> 16) & 1u)) >> 16;
    return (short)r;
}
__device__ __forceinline__ float b2f(short s) {
    unsigned int u = ((unsigned int)(unsigned short)s) << 16;
    return __builtin_bit_cast(float, u);
}

// async global->LDS, 16 B/lane. LDS dest = wave-uniform base + lane*16 [m104/m108].
__device__ __forceinline__ void cp16(const void* g, void* l) {
    __builtin_amdgcn_global_load_lds(
        (const __attribute__((address_space(1))) void*)g,
        (__attribute__((address_space(3))) void*)l, 16, 0, 0);
}

constexpr int EPI_XP  = 0;  // +bias, store bf16, atomic row-norm accumulate
constexpr int EPI_AT  = 1;  // 2/(Dcol[n]+Drow[m]) scale, store bf16
constexpr int EPI_BF  = 2;  // store bf16 (partial / plain)
constexpr int EPI_OUT = 3;  // +bias, relu, store f32

constexpr int ASRC_F32  = 0;  // A f32 global, convert during staging
constexpr int ASRC_BF16 = 1;  // A bf16 global, cp16 async staging
constexpr int ASRC_SUM2 = 2;  // A = bf16(p0) + bf16(p1), staged via VGPR

// Core: C = A @ Bt^T. TM x 128 tile, 256 threads. TM=128: wave-tile 64x64 (4x4
// frags); TM=64: wave-tile 32x64 (2x4). LDS unpadded stride 32 (cp16 mapping).
template<int EPI, int ASRC, int TM>
__device__ __forceinline__ void gemm_core(
    const void* __restrict__ Aptr, const void* __restrict__ Aptr2, int lda,
    const short* __restrict__ Bt, int ldb,
    int N, int K, int bm, int bn, int kbase,
    const float* __restrict__ bias,
    short* __restrict__ outb, float* __restrict__ outf,
    float* __restrict__ Dacc,
    const float* __restrict__ Drow, const float* __restrict__ Dcol)
{
    constexpr int FRM = TM / 32;            // 4 or 2
    __shared__ __align__(16) short As[TM * 32];
    __shared__ __align__(16) short Bs[128 * 32];

    const int tid  = threadIdx.x;
    const int wave = tid >> 6;
    const int lane = tid & 63;
    const int quad = lane >> 4;
    const int l15  = lane & 15;
    const int wm   = (wave >> 1) * (FRM * 16);
    const int wn   = (wave & 1) * 64;

    f32x4 acc[FRM][4];
#pragma unroll
    for (int i = 0; i < FRM; i++)
#pragma unroll
        for (int j = 0; j < 4; j++)
            acc[i][j] = f32x4{0.f, 0.f, 0.f, 0.f};

    for (int k0 = 0; k0 < K; k0 += 32) {
        const int kk = kbase + k0;
        if (ASRC == ASRC_F32) {
            const float* Af = (const float*)Aptr;
#pragma unroll
            for (int s = 0; s < TM * 8 / 256; s++) {
                int seg = tid + 256 * s;          // TM rows x 8 float4
                int row = seg >> 3, c4 = seg & 7;
                const float4 v = *(const float4*)&Af[(size_t)(bm + row) * lda + kk + c4 * 4];
                bf16x4 b;
                b[0] = f2b(v.x); b[1] = f2b(v.y); b[2] = f2b(v.z); b[3] = f2b(v.w);
                *(bf16x4*)&As[row * 32 + c4 * 4] = b;
            }
        } else if (ASRC == ASRC_BF16) {
            const short* Ab = (const short*)Aptr;
#pragma unroll
            for (int s = 0; s < TM / 64; s++) {
                int seg = tid + 256 * s;          // TM rows x 4 bf16x8
                int row = seg >> 2, c8 = seg & 3;
                cp16(&Ab[(size_t)(bm + row) * lda + kk + c8 * 8], &As[seg * 8]);
            }
        } else {                                  // ASRC_SUM2
            const short* A0 = (const short*)Aptr;
            const short* A1 = (const short*)Aptr2;
#pragma unroll
            for (int s = 0; s < TM / 64; s++) {
                int seg = tid + 256 * s;
                int row = seg >> 2, c8 = seg & 3;
                const size_t off = (size_t)(bm + row) * lda + kk + c8 * 8;
                bf16x8 a0 = *(const bf16x8*)&A0[off];
                bf16x8 a1 = *(const bf16x8*)&A1[off];
                bf16x8 o;
#pragma unroll
                for (int e = 0; e < 8; e++) o[e] = f2b(b2f(a0[e]) + b2f(a1[e]));
                *(bf16x8*)&As[seg * 8] = o;
            }
        }
#pragma unroll
        for (int s = 0; s < 2; s++) {
            int seg = tid + 256 * s;              // 128 rows x 4 bf16x8
            int row = seg >> 2, c8 = seg & 3;
            cp16(&Bt[(size_t)(bn + row) * ldb + kk + c8 * 8], &Bs[seg * 8]);
        }
        __syncthreads();

        bf16x8 af[FRM], bfr[4];
#pragma unroll
        for (int i = 0; i < FRM; i++)
            af[i] = *(const bf16x8*)&As[(wm + i * 16 + l15) * 32 + quad * 8];
#pragma unroll
        for (int j = 0; j < 4; j++)
            bfr[j] = *(const bf16x8*)&Bs[(wn + j * 16 + l15) * 32 + quad * 8];
#pragma unroll
        for (int i = 0; i < FRM; i++)
#pragma unroll
            for (int j = 0; j < 4; j++)
                acc[i][j] = __builtin_amdgcn_mfma_f32_16x16x32_bf16(af[i], bfr[j], acc[i][j], 0, 0, 0);
        __syncthreads();
    }

    // C/D layout: col = lane&15, row = quad*4 + r  [m89/m91]
#pragma unroll
    for (int im = 0; im < FRM; im++) {
#pragma unroll
        for (int r = 0; r < 4; r++) {
            const int gm = bm + wm + im * 16 + quad * 4 + r;
            if (EPI == EPI_XP) {
                float s = 0.f;
#pragma unroll
                for (int jn = 0; jn < 4; jn++) {
                    const int gn = bn + wn + jn * 16 + l15;
                    float v = acc[im][jn][r] + bias[gn];
                    outb[(size_t)gm * N + gn] = f2b(v);
                    s += v * v;
                }
#pragma unroll
                for (int m = 1; m < 16; m <<= 1) s += __shfl_xor(s, m, 64);
                if (l15 == 0) atomicAdd(&Dacc[gm], s);
            } else if (EPI == EPI_AT) {
                const float dy = Drow[gm];
#pragma unroll
                for (int jn = 0; jn < 4; jn++) {
                    const int gn = bn + wn + jn * 16 + l15;
                    float v = 2.f * acc[im][jn][r] / (Dcol[gn] + dy);
                    outb[(size_t)gm * N + gn] = f2b(v);
                }
            } else if (EPI == EPI_BF) {
#pragma unroll
                for (int jn = 0; jn < 4; jn++) {
                    const int gn = bn + wn + jn * 16 + l15;
                    outb[(size_t)gm * N + gn] = f2b(acc[im][jn][r]);
                }
            } else {
#pragma unroll
                for (int jn = 0; jn < 4; jn++) {
                    const int gn = bn + wn + jn * 16 + l15;
                    float v = acc[im][jn][r] + bias[gn];
                    outf[(size_t)gm * N + gn] = fmaxf(v, 0.f);
                }
            }
        }
    }
}

// G1/G2: xp/yp = x@W + b, row-norm accumulate. grid(4,128), TM=64.
__global__ __launch_bounds__(256)
void k_proj(const float* __restrict__ A, const short* __restrict__ Bt,
            const float* __restrict__ bias, short* __restrict__ outb,
            float* __restrict__ Dacc)
{
    gemm_core<EPI_XP, ASRC_F32, 64>(A, nullptr, 1024, Bt, 1024, 512, 1024,
                                    blockIdx.y * 64, blockIdx.x * 128, 0,
                                    bias, outb, nullptr, Dacc, nullptr, nullptr);
}

// G3: At[j,i]. flat grid 4096; 8x8-block supertile per XCD (2 MB ws fits L2).
__global__ __launch_bounds__(256)
void k_aff(const short* __restrict__ ypb, const short* __restrict__ xpb,
           short* __restrict__ At, const float* __restrict__ Dy,
           const float* __restrict__ Dx)
{
    const int flat = blockIdx.x;
    const int x  = flat & 7;          // XCD (round-robin dispatch)
    const int q  = flat >> 3;         // 0..511 within XCD
    const int st = q >> 6;            // supertile 0..7 within XCD
    const int w  = q & 63;
    const int s  = x * 8 + st;        // global supertile 0..63 (8x8 grid)
    const int bx = (s & 7) * 8 + (w & 7);
    const int by = (s >> 3) * 8 + (w >> 3);
    gemm_core<EPI_AT, ASRC_BF16, 128>(ypb, nullptr, 512, xpb, 512, 8192, 512,
                                      by * 128, bx * 128, 0,
                                      nullptr, At, nullptr, nullptr, Dy, Dx);
}

// G4: gwf partials = At@xp. flat grid 512; z=2 K-split; the 4 bn-blocks of a
// (bm,z) group land on one XCD so L2 serves 3 of their 4 At reads.
__global__ __launch_bounds__(256)
void k_agg(const short* __restrict__ At, const short* __restrict__ xpT,
           short* __restrict__ p0, short* __restrict__ p1)
{
    const int flat = blockIdx.x;
    const int x = flat & 7;           // XCD
    const int q = flat >> 3;          // 0..63 within XCD
    const int g = x * 16 + (q >> 2);  // group 0..127 = (z, bm)
    const int z = g >> 6;
    const int bm = (g & 63) * 128;
    const int bn = (q & 3) * 128;
    short* outb = z ? p1 : p0;
    gemm_core<EPI_BF, ASRC_BF16, 128>(At, nullptr, 8192, xpT, 8192, 512, 4096,
                                      bm, bn, z * 4096,
                                      nullptr, outb, nullptr, nullptr, nullptr, nullptr);
}

// G5: out = relu((p0+p1)@Wg + bg). grid(4,128), TM=64, A summed during staging.
__global__ __launch_bounds__(256)
void k_out(const short* __restrict__ p0, const short* __restrict__ p1,
           const short* __restrict__ WgT, const float* __restrict__ bg,
           float* __restrict__ out)
{
    gemm_core<EPI_OUT, ASRC_SUM2, 64>(p0, p1, 512, WgT, 512, 512, 512,
                                      blockIdx.y * 64, blockIdx.x * 128, 0,
                                      bg, nullptr, out, nullptr, nullptr, nullptr);
}

__global__ __launch_bounds__(256)
void transpose_f32_bf16(const float* __restrict__ in, short* __restrict__ out, int R, int C)
{
    __shared__ short t[32][33];
    const int tx = threadIdx.x, ty = threadIdx.y;
    const int bx = blockIdx.x * 32, by = blockIdx.y * 32;
#pragma unroll
    for (int i = 0; i < 32; i += 8)
        t[ty + i][tx] = f2b(in[(size_t)(by + ty + i) * C + bx + tx]);
    __syncthreads();
#pragma unroll
    for (int i = 0; i < 32; i += 8)
        out[(size_t)(bx + ty + i) * R + by + tx] = t[tx][ty + i];
}

__global__ __launch_bounds__(256)
void transpose_bf16(const short* __restrict__ in, short* __restrict__ out, int R, int C)
{
    __shared__ short t[32][33];
    const int tx = threadIdx.x, ty = threadIdx.y;
    const int bx = blockIdx.x * 32, by = blockIdx.y * 32;
#pragma unroll
    for (int i = 0; i < 32; i += 8)
        t[ty + i][tx] = in[(size_t)(by + ty + i) * C + bx + tx];
    __syncthreads();
#pragma unroll
    for (int i = 0; i < 32; i += 8)
        out[(size_t)(bx + ty + i) * R + by + tx] = t[tx][ty + i];
}

extern "C" void kernel_launch(void* const* d_in, const int* in_sizes, int n_in,
                              void* d_out, int out_size, void* d_ws, size_t ws_size,
                              hipStream_t stream)
{
    const float* x  = (const float*)d_in[0];
    const float* y  = (const float*)d_in[1];
    const float* Wx = (const float*)d_in[2];
    const float* bx = (const float*)d_in[3];
    const float* Wy = (const float*)d_in[4];
    const float* by = (const float*)d_in[5];
    const float* Wg = (const float*)d_in[6];
    const float* bg = (const float*)d_in[7];
    float* out = (float*)d_out;                // [8192, 512] f32

    char* p = (char*)d_ws;
    short* At   = (short*)p; p += (size_t)8192 * 8192 * 2;
    short* xpb  = (short*)p; p += (size_t)8192 * 512 * 2;
    short* ypb  = (short*)p; p += (size_t)8192 * 512 * 2;
    short* xpT  = (short*)p; p += (size_t)512 * 8192 * 2;
    short* WxT  = (short*)p; p += (size_t)512 * 1024 * 2;
    short* WyT  = (short*)p; p += (size_t)512 * 1024 * 2;
    short* WgT  = (short*)p; p += (size_t)512 * 512 * 2;
    float* Dx   = (float*)p; p += (size_t)8192 * 4;
    float* Dy   = (float*)p; p += (size_t)8192 * 4;
    // G4 partials alias xpb/ypb (dead after G3)
    short* p0 = xpb;
    short* p1 = ypb;

    hipMemsetAsync(Dx, 0, 2 * 8192 * sizeof(float), stream);  // Dx,Dy contiguous

    dim3 tb(32, 8);
    transpose_f32_bf16<<<dim3(512 / 32, 1024 / 32), tb, 0, stream>>>(Wx, WxT, 1024, 512);
    transpose_f32_bf16<<<dim3(512 / 32, 1024 / 32), tb, 0, stream>>>(Wy, WyT, 1024, 512);
    transpose_f32_bf16<<<dim3(512 / 32, 512 / 32),  tb, 0, stream>>>(Wg, WgT, 512, 512);

    k_proj<<<dim3(4, 128), 256, 0, stream>>>(x, WxT, bx, xpb, Dx);
    k_proj<<<dim3(4, 128), 256, 0, stream>>>(y, WyT, by, ypb, Dy);

    transpose_bf16<<<dim3(512 / 32, 8192 / 32), tb, 0, stream>>>(xpb, xpT, 8192, 512);

    k_aff<<<4096, 256, 0, stream>>>(ypb, xpb, At, Dy, Dx);

    k_agg<<<512, 256, 0, stream>>>(At, xpT, p0, p1);

    k_out<<<dim3(4, 128), 256, 0, stream>>>(p0, p1, WgT, bg, out);
}